// Round 3
// baseline (720.685 us; speedup 1.0000x reference)
//
#include <hip/hip_runtime.h>
#include <math.h>
#include <stdint.h>

namespace {

constexpr int T = 50;
constexpr int NB = 32768;
constexpr int H = 128;
constexpr int NTHREADS = 256;   // 4 waves; each wave owns 32 output cols
constexpr int BLK_ROWS = 32;    // 2 M-tiles of 16 rows; 1024 blocks = 4/CU
constexpr int SH_STRIDE = 132;  // u32 words per h row (128 + 4 pad)

typedef float v4f __attribute__((ext_vector_type(4)));
typedef float v2f __attribute__((ext_vector_type(2)));
typedef unsigned int v4u __attribute__((ext_vector_type(4)));
typedef short short8 __attribute__((ext_vector_type(8)));

union FU { float f; uint32_t u; };
union U8 { uint32_t u[4]; short8 v; };

// v_perm_b32 byte-select packers (1 VALU op each)
__device__ __forceinline__ uint32_t perm_hi(uint32_t odd, uint32_t even) {
  // top16(odd) : top16(even)
  return __builtin_amdgcn_perm(odd, even, 0x07060302u);
}
__device__ __forceinline__ uint32_t perm_lo(uint32_t odd, uint32_t even) {
  // low16(odd) : low16(even)
  return __builtin_amdgcn_perm(odd, even, 0x05040100u);
}

// 2-way bf16 split, raw words: top16(araw)=hi plane, top16(rraw)=mid plane
__device__ __forceinline__ void split2raw(float a, uint32_t& araw, uint32_t& rraw) {
  FU c0; c0.f = a;
  FU fh; fh.u = c0.u & 0xFFFF0000u;
  FU r;  r.f  = a - fh.f;   // exact
  araw = c0.u; rraw = r.u;
}
// 3-way exact bf16 split (prologue only)
__device__ __forceinline__ void split3(float a, uint32_t& hi, uint32_t& mid, uint32_t& lo) {
  FU c0; c0.f = a;
  uint32_t uh = c0.u & 0xFFFF0000u;
  FU fh; fh.u = uh;
  float r1 = a - fh.f;
  FU c1; c1.f = r1;
  uint32_t um = c1.u & 0xFFFF0000u;
  FU fm; fm.u = um;
  float r2 = r1 - fm.f;
  FU c2; c2.f = r2;
  hi = uh; mid = um; lo = c2.u;
}

__device__ __forceinline__ v4f mfma16(short8 a, short8 b, v4f c) {
  return __builtin_amdgcn_mfma_f32_16x16x32_bf16(a, b, c, 0, 0, 0);
}

// VALU-pipe butterfly add (replaces ds_bpermute __shfl_xor)
template<int CTRL>
__device__ __forceinline__ float dpp_radd(float x) {
  FU a; a.f = x;
  FU b; b.u = (uint32_t)__builtin_amdgcn_update_dpp(0, (int)a.u, CTRL, 0xF, 0xF, true);
  return x + b.f;
}
// sum over the 16 lanes of each lane-group (o = lane&15); result in all 16.
__device__ __forceinline__ float red16(float x) {
  x = dpp_radd<0xB1>(x);    // quad_perm xor1
  x = dpp_radd<0x4E>(x);    // quad_perm xor2
  x = dpp_radd<0x141>(x);   // row_half_mirror (xor4)
  x = dpp_radd<0x140>(x);   // row_mirror (xor8)
  return x;
}

__global__ __launch_bounds__(NTHREADS, 4)
void fwdsim7(const float* __restrict__ proj,   // (B, 64)
             const float* __restrict__ idm,    // (B, T, 12)
             const float* __restrict__ merg,   // (B, T, 3)
             const float* __restrict__ W1,     // (73, 128)
             const float* __restrict__ b1,     // (128)
             const float* __restrict__ W2,     // (128, 128)
             const float* __restrict__ b2,     // (128)
             const float* __restrict__ W3,     // (128, 1)
             const float* __restrict__ b3,     // (1)
             const float* __restrict__ smean,  // (6)
             const float* __restrict__ svar,   // (6)
             float* __restrict__ out)          // (B, T)
{
  // h exchange: [row 32][132] packed bf16 hi|mid (col 0..127 live, 4 pad)
  __shared__ __align__(16) uint32_t sH[BLK_ROWS * SH_STRIDE];   // 16896 B
  // layer-3 partials: [buf][row 32][member 4]
  __shared__ __align__(16) float sAct[2][BLK_ROWS][4];          // 1024 B
  // output staging (coalesced flush at end)
  __shared__ __align__(16) float sOut[BLK_ROWS * T];            // 6400 B
  // total 24320 B -> 4 blocks/CU by LDS; VGPR<=128 -> 16 waves/CU

  const int tid  = threadIdx.x;
  const int wave = tid >> 6;    // 0..3: owns output cols wave*32 .. wave*32+31
  const int lane = tid & 63;
  const int gq   = lane >> 4;   // 0..3
  const int o    = lane & 15;   // 0..15
  const int row0 = blockIdx.x * BLK_ROWS;

  // ---- scalars ----
  float mean[6], istd[6];
#pragma unroll
  for (int c = 0; c < 6; ++c) { mean[c] = smean[c]; istd[c] = 1.0f / sqrtf(svar[c]); }
  const float b3v = b3[0];
  float b1c[2], b2c[2], W3c[2];
#pragma unroll
  for (int ntl = 0; ntl < 2; ++ntl) {
    const int n = (wave * 2 + ntl) * 16 + o;
    b1c[ntl] = b1[n]; b2c[ntl] = b2[n]; W3c[ntl] = W3[n];
  }

  // ---- W1 env rows 64..72 -> persistent register B-frags (2-plane, K pad 32) ----
  short8 ebh[2], ebm[2];
#pragma unroll
  for (int ntl = 0; ntl < 2; ++ntl) {
    const int n = (wave * 2 + ntl) * 16 + o;
    uint32_t hr[8], mr[8];
#pragma unroll
    for (int j = 0; j < 8; ++j) {
      const int k = gq * 8 + j;
      const float w = (k < 9) ? W1[(64 + k) * H + n] : 0.f;
      split2raw(w, hr[j], mr[j]);
    }
    U8 fh, fm;
#pragma unroll
    for (int d = 0; d < 4; ++d) {
      fh.u[d] = perm_hi(hr[2*d+1], hr[2*d]);
      fm.u[d] = perm_hi(mr[2*d+1], mr[2*d]);
    }
    ebh[ntl] = fh.v; ebm[ntl] = fm.v;
  }

  // ---- W1[0:64] 3-plane frags (prologue-only, registers) ----
  short8 w1h[4], w1m[4], w1l[4];   // [kt*2+ntl]
#pragma unroll
  for (int kt = 0; kt < 2; ++kt)
#pragma unroll
    for (int ntl = 0; ntl < 2; ++ntl) {
      const int k0 = kt * 32 + gq * 8;
      const int n  = (wave * 2 + ntl) * 16 + o;
      uint32_t hi[8], mi[8], lo[8];
#pragma unroll
      for (int j = 0; j < 8; ++j) split3(W1[(k0 + j) * H + n], hi[j], mi[j], lo[j]);
      U8 fh, fm, fl;
#pragma unroll
      for (int d = 0; d < 4; ++d) {
        fh.u[d] = perm_hi(hi[2*d+1], hi[2*d]);
        fm.u[d] = perm_hi(mi[2*d+1], mi[2*d]);
        fl.u[d] = perm_hi(lo[2*d+1], lo[2*d]);
      }
      w1h[kt*2+ntl] = fh.v; w1m[kt*2+ntl] = fm.v; w1l[kt*2+ntl] = fl.v;
    }

  // ---- base1 = b1 + proj @ W1[0:64] via 6-term exact-split MFMA -> registers ----
  // base[mt*2+ntl][r] = base1 for row mt*16+4gq+r, col (wave*2+ntl)*16+o
  v4f base[4];
#pragma unroll
  for (int mt = 0; mt < 2; ++mt) {
    const int row = row0 + mt * 16 + o;
    short8 pah[2], pam[2], pal[2];
#pragma unroll
    for (int kt = 0; kt < 2; ++kt) {
      const float* pp = proj + (size_t)row * 64 + kt * 32 + gq * 8;
      v4f p0 = *(const v4f*)pp;
      v4f p1 = *(const v4f*)(pp + 4);
      uint32_t hi[8], mi[8], lo[8];
#pragma unroll
      for (int e = 0; e < 4; ++e) split3(p0[e], hi[e],   mi[e],   lo[e]);
#pragma unroll
      for (int e = 0; e < 4; ++e) split3(p1[e], hi[4+e], mi[4+e], lo[4+e]);
      U8 uh, um, ul;
#pragma unroll
      for (int d = 0; d < 4; ++d) {
        uh.u[d] = perm_hi(hi[2*d+1], hi[2*d]);
        um.u[d] = perm_hi(mi[2*d+1], mi[2*d]);
        ul.u[d] = perm_hi(lo[2*d+1], lo[2*d]);
      }
      pah[kt] = uh.v; pam[kt] = um.v; pal[kt] = ul.v;
    }
#pragma unroll
    for (int ntl = 0; ntl < 2; ++ntl) {
      v4f acc = (v4f){b1c[ntl], b1c[ntl], b1c[ntl], b1c[ntl]};
#pragma unroll
      for (int kt = 0; kt < 2; ++kt) {
        short8 bh = w1h[kt*2+ntl], bm = w1m[kt*2+ntl], bl = w1l[kt*2+ntl];
        acc = mfma16(pah[kt], bl, acc);
        acc = mfma16(pal[kt], bh, acc);
        acc = mfma16(pam[kt], bm, acc);
        acc = mfma16(pah[kt], bm, acc);
        acc = mfma16(pam[kt], bh, acc);
        acc = mfma16(pah[kt], bh, acc);
      }
      base[mt*2+ntl] = acc;
    }
  }

  // ---- W2 -> persistent register B-frags, this wave's 2 col-tiles only ----
  short8 w2h[8], w2m[8];   // [kt*2+ntl], kt 0..3
#pragma unroll
  for (int kt = 0; kt < 4; ++kt)
#pragma unroll
    for (int ntl = 0; ntl < 2; ++ntl) {
      const int k0 = kt * 32 + gq * 8;
      const int n  = (wave * 2 + ntl) * 16 + o;
      uint32_t hr[8], mr[8];
#pragma unroll
      for (int j = 0; j < 8; ++j) split2raw(W2[(k0 + j) * H + n], hr[j], mr[j]);
      U8 fh, fm;
#pragma unroll
      for (int d = 0; d < 4; ++d) {
        fh.u[d] = perm_hi(hr[2*d+1], hr[2*d]);
        fm.u[d] = perm_hi(mr[2*d+1], mr[2*d]);
      }
      w2h[kt*2+ntl] = fh.v;
      w2m[kt*2+ntl] = fm.v;
    }

  // ---- recurrent state: lane handles rows mt*16+o, replicated over gq/waves ----
  float ego_v[2], ego_x[2], act[2] = {0.f, 0.f};
  const float* idmp[2];
  const float* mrgp[2];
  v4f sa[2]; v2f fb[2]; float exr[2], m0[2], m1[2], m2[2];
#pragma unroll
  for (int mt = 0; mt < 2; ++mt) {
    idmp[mt] = idm  + (size_t)(row0 + mt*16 + o) * (T*12);
    mrgp[mt] = merg + (size_t)(row0 + mt*16 + o) * (T*3);
    sa[mt] = *(const v4f*)idmp[mt];
    fb[mt] = *(const v2f*)(idmp[mt] + 4);
    exr[mt] = idmp[mt][11];
    m0[mt] = mrgp[mt][0]; m1[mt] = mrgp[mt][1]; m2[mt] = mrgp[mt][2];
  }

  int buf = 0;

#pragma unroll 1
  for (int t = 0; t < T; ++t) {
    // ======== phase A: state + env + layer 1 -> sH (own 32 cols) ========
#pragma unroll
    for (int mt = 0; mt < 2; ++mt) {
      const float s0 = sa[mt][0], fv = sa[mt][1], mv = sa[mt][2], s3 = sa[mt][3];
      const float fgx = fb[mt][0], mgx = fb[mt][1];
      const float ex = exr[mt];
      if (t == 0) { ego_v[mt] = s0; ego_x[mt] = s3; }
      else {
        ego_v[mt] += act[mt] * 0.1f;
        ego_x[mt] += ego_v[mt] * 0.1f + act[mt] * 0.005f;
      }
      float xk[9];
      xk[0] = (ego_v[mt]                                      - mean[0]) * istd[0];
      xk[1] = (fv                                             - mean[1]) * istd[1];
      xk[2] = (ego_v[mt] - fv                                 - mean[2]) * istd[2];
      xk[3] = (fgx - ego_x[mt]                                - mean[3]) * istd[3];
      xk[4] = ((ego_v[mt] - mv) * ex                          - mean[4]) * istd[4];
      xk[5] = ((mgx - ego_x[mt]) * ex + (1.0f - ex) * 100.0f  - mean[5]) * istd[5];
      xk[6] = m0[mt]; xk[7] = m1[mt]; xk[8] = m2[mt];

      // env A-frag: A[m=o][k=8gq+j]; dims 9..31 zero
      uint32_t hr[8], mr[8];
#pragma unroll
      for (int j = 0; j < 8; ++j) {
        float v = (gq == 0) ? xk[j] : ((gq == 1 && j == 0) ? xk[8] : 0.f);
        split2raw(v, hr[j], mr[j]);
      }
      U8 uh, um;
#pragma unroll
      for (int d = 0; d < 4; ++d) {
        uh.u[d] = perm_hi(hr[2*d+1], hr[2*d]);
        um.u[d] = perm_hi(mr[2*d+1], mr[2*d]);
      }
      short8 eh = uh.v, em = um.v;

#pragma unroll
      for (int ntl = 0; ntl < 2; ++ntl) {
        v4f a1 = base[mt*2+ntl];
        a1 = mfma16(eh, ebm[ntl], a1);
        a1 = mfma16(em, ebh[ntl], a1);
        a1 = mfma16(eh, ebh[ntl], a1);
#pragma unroll
        for (int r = 0; r < 4; ++r) {
          const float hv = fmaxf(a1[r], 0.f);
          uint32_t hu, ru; split2raw(hv, hu, ru);
          sH[(mt*16 + 4*gq + r) * SH_STRIDE + (wave*2+ntl)*16 + o] = perm_hi(hu, ru);
        }
      }
    }

    __syncthreads();   // B1: full h visible

    // issue next-step input loads; they fly under layer 2, drained by use at t+1
    v4f nsa[2]; v2f nfb[2]; float nex[2], nm0[2], nm1[2], nm2[2];
    {
      const int tn = (t + 1 < T) ? t + 1 : t;
#pragma unroll
      for (int mt = 0; mt < 2; ++mt) {
        const float* ip = idmp[mt] + tn * 12;
        nsa[mt] = *(const v4f*)ip;  nfb[mt] = *(const v2f*)(ip + 4);  nex[mt] = ip[11];
        const float* mp = mrgp[mt] + tn * 3;
        nm0[mt] = mp[0]; nm1[mt] = mp[1]; nm2[mt] = mp[2];
      }
    }

    // ======== phase B: layer 2 (full K from sH) + layer-3 partial ========
#pragma unroll
    for (int mt = 0; mt < 2; ++mt) {
      v4f acc2[2];
#pragma unroll
      for (int ntl = 0; ntl < 2; ++ntl)
        acc2[ntl] = (v4f){b2c[ntl], b2c[ntl], b2c[ntl], b2c[ntl]};

#pragma unroll
      for (int kt = 0; kt < 4; ++kt) {
        const uint32_t* src = &sH[(mt*16 + o) * SH_STRIDE + kt*32 + gq*8];
        v4u q0 = *(const v4u*)src;
        v4u q1 = *(const v4u*)(src + 4);
        uint32_t u[8] = {q0[0], q0[1], q0[2], q0[3], q1[0], q1[1], q1[2], q1[3]};
        U8 uh, um;
#pragma unroll
        for (int d = 0; d < 4; ++d) {
          uh.u[d] = perm_hi(u[2*d+1], u[2*d]);   // hi plane
          um.u[d] = perm_lo(u[2*d+1], u[2*d]);   // mid plane
        }
        short8 ah = uh.v, am = um.v;
#pragma unroll
        for (int ntl = 0; ntl < 2; ++ntl) {
          acc2[ntl] = mfma16(ah, w2m[kt*2+ntl], acc2[ntl]);
          acc2[ntl] = mfma16(am, w2h[kt*2+ntl], acc2[ntl]);
          acc2[ntl] = mfma16(ah, w2h[kt*2+ntl], acc2[ntl]);
        }
      }

      // layer-3 partial over this wave's 32 cols
      v4f part = (v4f){0.f, 0.f, 0.f, 0.f};
#pragma unroll
      for (int ntl = 0; ntl < 2; ++ntl)
#pragma unroll
        for (int r = 0; r < 4; ++r)
          part[r] += fmaxf(acc2[ntl][r], 0.f) * W3c[ntl];
#pragma unroll
      for (int r = 0; r < 4; ++r) part[r] = red16(part[r]);   // VALU butterfly

      // spread store: lane (gq, o<4) writes row mt*16+4gq+o, one ds_write
      const float pv = (o & 2) ? ((o & 1) ? part[3] : part[2])
                               : ((o & 1) ? part[1] : part[0]);
      if (o < 4) sAct[buf][mt*16 + 4*gq + o][wave] = pv;
    }

    __syncthreads();   // B2: partials visible; sH reads done (WAR for t+1)

    // act = sum of 4 member partials + b3
#pragma unroll
    for (int mt = 0; mt < 2; ++mt) {
      v4f pa = *(const v4f*)&sAct[buf][mt*16 + o][0];
      act[mt] = ((pa[0] + pa[1]) + (pa[2] + pa[3])) + b3v;
    }
    if (wave == 0 && gq == 0) {
#pragma unroll
      for (int mt = 0; mt < 2; ++mt)
        sOut[(mt*16 + o) * T + t] = act[mt];
    }

    // roll prefetched inputs
#pragma unroll
    for (int mt = 0; mt < 2; ++mt) {
      sa[mt] = nsa[mt]; fb[mt] = nfb[mt]; exr[mt] = nex[mt];
      m0[mt] = nm0[mt]; m1[mt] = nm1[mt]; m2[mt] = nm2[mt];
    }
    buf ^= 1;
  }

  // ---- coalesced output flush ----
  __syncthreads();
  float* obase = out + (size_t)row0 * T;
  for (int idx = tid; idx < BLK_ROWS * T; idx += NTHREADS)
    obase[idx] = sOut[idx];
}

}  // namespace

extern "C" void kernel_launch(void* const* d_in, const int* in_sizes, int n_in,
                              void* d_out, int out_size, void* d_ws, size_t ws_size,
                              hipStream_t stream) {
  const float* proj  = (const float*)d_in[0];
  const float* idm   = (const float*)d_in[1];
  const float* merg  = (const float*)d_in[2];
  const float* W1    = (const float*)d_in[3];
  const float* b1    = (const float*)d_in[4];
  const float* W2    = (const float*)d_in[5];
  const float* b2    = (const float*)d_in[6];
  const float* W3    = (const float*)d_in[7];
  const float* b3    = (const float*)d_in[8];
  const float* smean = (const float*)d_in[9];
  const float* svar  = (const float*)d_in[10];
  // d_in[11] = rollout_len (fixed 50)

  dim3 grid(NB / BLK_ROWS);   // 1024 blocks -> 4 per CU, single pass
  dim3 block(NTHREADS);       // 256 threads = 4 waves, 32 rows
  hipLaunchKernelGGL(fwdsim7, grid, block, 0, stream,
                     proj, idm, merg, W1, b1, W2, b2, W3, b3, smean, svar,
                     (float*)d_out);
}

// Round 4
// 380.872 us; speedup vs baseline: 1.8922x; 1.8922x over previous
//
#include <hip/hip_runtime.h>
#include <math.h>
#include <stdint.h>

namespace {

constexpr int T = 50;
constexpr int NB = 32768;
constexpr int H = 128;
constexpr int NTHREADS = 256;   // 4 waves; each wave owns 32 output cols
constexpr int BLK_ROWS = 32;    // 2 M-tiles of 16 rows; 1024 blocks = 4/CU
constexpr int SH_STRIDE = 132;  // u32 words per h row (128 + 4 pad)

typedef float v4f __attribute__((ext_vector_type(4)));
typedef float v2f __attribute__((ext_vector_type(2)));
typedef unsigned int v4u __attribute__((ext_vector_type(4)));
typedef short short8 __attribute__((ext_vector_type(8)));

union FU { float f; uint32_t u; };
union U8 { uint32_t u[4]; short8 v; };

// v_perm_b32 byte-select packers (1 VALU op each)
__device__ __forceinline__ uint32_t perm_hi(uint32_t odd, uint32_t even) {
  // top16(odd) : top16(even)
  return __builtin_amdgcn_perm(odd, even, 0x07060302u);
}
__device__ __forceinline__ uint32_t perm_lo(uint32_t odd, uint32_t even) {
  // low16(odd) : low16(even)
  return __builtin_amdgcn_perm(odd, even, 0x05040100u);
}

// 2-way bf16 split, raw words: top16(araw)=hi plane, top16(rraw)=mid plane
__device__ __forceinline__ void split2raw(float a, uint32_t& araw, uint32_t& rraw) {
  FU c0; c0.f = a;
  FU fh; fh.u = c0.u & 0xFFFF0000u;
  FU r;  r.f  = a - fh.f;   // exact
  araw = c0.u; rraw = r.u;
}
// 3-way exact bf16 split (prologue only)
__device__ __forceinline__ void split3(float a, uint32_t& hi, uint32_t& mid, uint32_t& lo) {
  FU c0; c0.f = a;
  uint32_t uh = c0.u & 0xFFFF0000u;
  FU fh; fh.u = uh;
  float r1 = a - fh.f;
  FU c1; c1.f = r1;
  uint32_t um = c1.u & 0xFFFF0000u;
  FU fm; fm.u = um;
  float r2 = r1 - fm.f;
  FU c2; c2.f = r2;
  hi = uh; mid = um; lo = c2.u;
}

__device__ __forceinline__ v4f mfma16(short8 a, short8 b, v4f c) {
  return __builtin_amdgcn_mfma_f32_16x16x32_bf16(a, b, c, 0, 0, 0);
}

// VALU-pipe butterfly add (replaces ds_bpermute __shfl_xor)
template<int CTRL>
__device__ __forceinline__ float dpp_radd(float x) {
  FU a; a.f = x;
  FU b; b.u = (uint32_t)__builtin_amdgcn_update_dpp(0, (int)a.u, CTRL, 0xF, 0xF, true);
  return x + b.f;
}
// sum over the 16 lanes of each lane-group (o = lane&15); result in all 16.
__device__ __forceinline__ float red16(float x) {
  x = dpp_radd<0xB1>(x);    // quad_perm xor1
  x = dpp_radd<0x4E>(x);    // quad_perm xor2
  x = dpp_radd<0x141>(x);   // row_half_mirror (xor4)
  x = dpp_radd<0x140>(x);   // row_mirror (xor8)
  return x;
}

__global__ __launch_bounds__(NTHREADS, 2)   // cap 256 VGPR: NO spills (R3 lesson)
void fwdsim8(const float* __restrict__ proj,   // (B, 64)
             const float* __restrict__ idm,    // (B, T, 12)
             const float* __restrict__ merg,   // (B, T, 3)
             const float* __restrict__ W1,     // (73, 128)
             const float* __restrict__ b1,     // (128)
             const float* __restrict__ W2,     // (128, 128)
             const float* __restrict__ b2,     // (128)
             const float* __restrict__ W3,     // (128, 1)
             const float* __restrict__ b3,     // (1)
             const float* __restrict__ smean,  // (6)
             const float* __restrict__ svar,   // (6)
             float* __restrict__ out)          // (B, T)
{
  // h exchange: [row 32][132] packed bf16 hi|mid (col 0..127 live, 4 pad)
  __shared__ __align__(16) uint32_t sH[BLK_ROWS * SH_STRIDE];   // 16896 B
  // layer-3 partials: [buf][row 32][member 4]
  __shared__ __align__(16) float sAct[2][BLK_ROWS][4];          // 1024 B
  // output staging (coalesced flush at end)
  __shared__ __align__(16) float sOut[BLK_ROWS * T];            // 6400 B
  // total 24320 B -> LDS allows 6 blocks/CU; grid gives 4

  const int tid  = threadIdx.x;
  const int wave = tid >> 6;    // 0..3: owns output cols wave*32 .. wave*32+31
  const int lane = tid & 63;
  const int gq   = lane >> 4;   // 0..3
  const int o    = lane & 15;   // 0..15
  const int row0 = blockIdx.x * BLK_ROWS;

  // ---- scalars: xk = v*istd + off with off = -mean*istd ----
  float istd[6], off[6];
#pragma unroll
  for (int c = 0; c < 6; ++c) {
    istd[c] = 1.0f / sqrtf(svar[c]);
    off[c]  = -smean[c] * istd[c];
  }
  const float b3v = b3[0];
  float b1c[2], b2c[2], W3c[2];
#pragma unroll
  for (int ntl = 0; ntl < 2; ++ntl) {
    const int n = (wave * 2 + ntl) * 16 + o;
    b1c[ntl] = b1[n]; b2c[ntl] = b2[n]; W3c[ntl] = W3[n];
  }

  // ---- W1 env rows 64..72 -> persistent register B-frags (2-plane, K pad 32) ----
  short8 ebh[2], ebm[2];
#pragma unroll
  for (int ntl = 0; ntl < 2; ++ntl) {
    const int n = (wave * 2 + ntl) * 16 + o;
    uint32_t hr[8], mr[8];
#pragma unroll
    for (int j = 0; j < 8; ++j) {
      const int k = gq * 8 + j;
      const float w = (k < 9) ? W1[(64 + k) * H + n] : 0.f;
      split2raw(w, hr[j], mr[j]);
    }
    U8 fh, fm;
#pragma unroll
    for (int d = 0; d < 4; ++d) {
      fh.u[d] = perm_hi(hr[2*d+1], hr[2*d]);
      fm.u[d] = perm_hi(mr[2*d+1], mr[2*d]);
    }
    ebh[ntl] = fh.v; ebm[ntl] = fm.v;
  }

  // ---- W1[0:64] 3-plane frags (prologue-only, registers) ----
  short8 w1h[4], w1m[4], w1l[4];   // [kt*2+ntl]
#pragma unroll
  for (int kt = 0; kt < 2; ++kt)
#pragma unroll
    for (int ntl = 0; ntl < 2; ++ntl) {
      const int k0 = kt * 32 + gq * 8;
      const int n  = (wave * 2 + ntl) * 16 + o;
      uint32_t hi[8], mi[8], lo[8];
#pragma unroll
      for (int j = 0; j < 8; ++j) split3(W1[(k0 + j) * H + n], hi[j], mi[j], lo[j]);
      U8 fh, fm, fl;
#pragma unroll
      for (int d = 0; d < 4; ++d) {
        fh.u[d] = perm_hi(hi[2*d+1], hi[2*d]);
        fm.u[d] = perm_hi(mi[2*d+1], mi[2*d]);
        fl.u[d] = perm_hi(lo[2*d+1], lo[2*d]);
      }
      w1h[kt*2+ntl] = fh.v; w1m[kt*2+ntl] = fm.v; w1l[kt*2+ntl] = fl.v;
    }

  // ---- base1 = b1 + proj @ W1[0:64] via 6-term exact-split MFMA -> registers ----
  // base[mt*2+ntl][r] = base1 for row mt*16+4gq+r, col (wave*2+ntl)*16+o
  v4f base[4];
#pragma unroll
  for (int mt = 0; mt < 2; ++mt) {
    const int row = row0 + mt * 16 + o;
    short8 pah[2], pam[2], pal[2];
#pragma unroll
    for (int kt = 0; kt < 2; ++kt) {
      const float* pp = proj + (size_t)row * 64 + kt * 32 + gq * 8;
      v4f p0 = *(const v4f*)pp;
      v4f p1 = *(const v4f*)(pp + 4);
      uint32_t hi[8], mi[8], lo[8];
#pragma unroll
      for (int e = 0; e < 4; ++e) split3(p0[e], hi[e],   mi[e],   lo[e]);
#pragma unroll
      for (int e = 0; e < 4; ++e) split3(p1[e], hi[4+e], mi[4+e], lo[4+e]);
      U8 uh, um, ul;
#pragma unroll
      for (int d = 0; d < 4; ++d) {
        uh.u[d] = perm_hi(hi[2*d+1], hi[2*d]);
        um.u[d] = perm_hi(mi[2*d+1], mi[2*d]);
        ul.u[d] = perm_hi(lo[2*d+1], lo[2*d]);
      }
      pah[kt] = uh.v; pam[kt] = um.v; pal[kt] = ul.v;
    }
#pragma unroll
    for (int ntl = 0; ntl < 2; ++ntl) {
      v4f acc = (v4f){b1c[ntl], b1c[ntl], b1c[ntl], b1c[ntl]};
#pragma unroll
      for (int kt = 0; kt < 2; ++kt) {
        short8 bh = w1h[kt*2+ntl], bm = w1m[kt*2+ntl], bl = w1l[kt*2+ntl];
        acc = mfma16(pah[kt], bl, acc);
        acc = mfma16(pal[kt], bh, acc);
        acc = mfma16(pam[kt], bm, acc);
        acc = mfma16(pah[kt], bm, acc);
        acc = mfma16(pam[kt], bh, acc);
        acc = mfma16(pah[kt], bh, acc);
      }
      base[mt*2+ntl] = acc;
    }
  }

  // ---- W2 -> persistent register B-frags, this wave's 2 col-tiles only ----
  short8 w2h[8], w2m[8];   // [kt*2+ntl], kt 0..3
#pragma unroll
  for (int kt = 0; kt < 4; ++kt)
#pragma unroll
    for (int ntl = 0; ntl < 2; ++ntl) {
      const int k0 = kt * 32 + gq * 8;
      const int n  = (wave * 2 + ntl) * 16 + o;
      uint32_t hr[8], mr[8];
#pragma unroll
      for (int j = 0; j < 8; ++j) split2raw(W2[(k0 + j) * H + n], hr[j], mr[j]);
      U8 fh, fm;
#pragma unroll
      for (int d = 0; d < 4; ++d) {
        fh.u[d] = perm_hi(hr[2*d+1], hr[2*d]);
        fm.u[d] = perm_hi(mr[2*d+1], mr[2*d]);
      }
      w2h[kt*2+ntl] = fh.v;
      w2m[kt*2+ntl] = fm.v;
    }

  // ---- recurrent state: lane handles rows mt*16+o, replicated over gq/waves ----
  float ego_v[2], ego_x[2], act[2] = {0.f, 0.f};
  const float* idmp[2];
  const float* mrgp[2];
  v4f sa[2]; v2f fb[2]; float exr[2], m0[2], m1[2], m2[2];
#pragma unroll
  for (int mt = 0; mt < 2; ++mt) {
    idmp[mt] = idm  + (size_t)(row0 + mt*16 + o) * (T*12);
    mrgp[mt] = merg + (size_t)(row0 + mt*16 + o) * (T*3);
    sa[mt] = *(const v4f*)idmp[mt];
    fb[mt] = *(const v2f*)(idmp[mt] + 4);
    exr[mt] = idmp[mt][11];
    m0[mt] = mrgp[mt][0]; m1[mt] = mrgp[mt][1]; m2[mt] = mrgp[mt][2];
  }

  int buf = 0;

#pragma unroll 1
  for (int t = 0; t < T; ++t) {
    // ======== phase A: state + env + layer 1 -> sH (own 32 cols) ========
#pragma unroll
    for (int mt = 0; mt < 2; ++mt) {
      const float s0 = sa[mt][0], fv = sa[mt][1], mv = sa[mt][2], s3 = sa[mt][3];
      const float fgx = fb[mt][0], mgx = fb[mt][1];
      const float ex = exr[mt];
      if (t == 0) { ego_v[mt] = s0; ego_x[mt] = s3; }
      else {
        ego_v[mt] += act[mt] * 0.1f;
        ego_x[mt] += ego_v[mt] * 0.1f + act[mt] * 0.005f;
      }
      float xk[9];
      xk[0] = ego_v[mt]                                     * istd[0] + off[0];
      xk[1] = fv                                            * istd[1] + off[1];
      xk[2] = (ego_v[mt] - fv)                              * istd[2] + off[2];
      xk[3] = (fgx - ego_x[mt])                             * istd[3] + off[3];
      xk[4] = ((ego_v[mt] - mv) * ex)                       * istd[4] + off[4];
      xk[5] = ((mgx - ego_x[mt]) * ex + (1.0f - ex) * 100.0f) * istd[5] + off[5];
      xk[6] = m0[mt]; xk[7] = m1[mt]; xk[8] = m2[mt];

      // env A-frag: A[m=o][k=8gq+j]; dims 9..31 zero
      uint32_t hr[8], mr[8];
#pragma unroll
      for (int j = 0; j < 8; ++j) {
        float v = (gq == 0) ? xk[j] : ((gq == 1 && j == 0) ? xk[8] : 0.f);
        split2raw(v, hr[j], mr[j]);
      }
      U8 uh, um;
#pragma unroll
      for (int d = 0; d < 4; ++d) {
        uh.u[d] = perm_hi(hr[2*d+1], hr[2*d]);
        um.u[d] = perm_hi(mr[2*d+1], mr[2*d]);
      }
      short8 eh = uh.v, em = um.v;

#pragma unroll
      for (int ntl = 0; ntl < 2; ++ntl) {
        v4f a1 = base[mt*2+ntl];
        a1 = mfma16(eh, ebm[ntl], a1);
        a1 = mfma16(em, ebh[ntl], a1);
        a1 = mfma16(eh, ebh[ntl], a1);
#pragma unroll
        for (int r = 0; r < 4; ++r) {
          const float hv = fmaxf(a1[r], 0.f);
          uint32_t hu, ru; split2raw(hv, hu, ru);
          sH[(mt*16 + 4*gq + r) * SH_STRIDE + (wave*2+ntl)*16 + o] = perm_hi(hu, ru);
        }
      }
    }

    __syncthreads();   // B1: full h visible

    // issue next-step input loads; they fly under layer 2
    v4f nsa[2]; v2f nfb[2]; float nex[2], nm0[2], nm1[2], nm2[2];
    {
      const int tn = (t + 1 < T) ? t + 1 : t;
#pragma unroll
      for (int mt = 0; mt < 2; ++mt) {
        const float* ip = idmp[mt] + tn * 12;
        nsa[mt] = *(const v4f*)ip;  nfb[mt] = *(const v2f*)(ip + 4);  nex[mt] = ip[11];
        const float* mp = mrgp[mt] + tn * 3;
        nm0[mt] = mp[0]; nm1[mt] = mp[1]; nm2[mt] = mp[2];
      }
    }

    // ======== phase B: layer 2 (full K from sH) + layer-3 partial ========
#pragma unroll
    for (int mt = 0; mt < 2; ++mt) {
      v4f acc2[2];
#pragma unroll
      for (int ntl = 0; ntl < 2; ++ntl)
        acc2[ntl] = (v4f){b2c[ntl], b2c[ntl], b2c[ntl], b2c[ntl]};

#pragma unroll
      for (int kt = 0; kt < 4; ++kt) {
        const uint32_t* src = &sH[(mt*16 + o) * SH_STRIDE + kt*32 + gq*8];
        v4u q0 = *(const v4u*)src;
        v4u q1 = *(const v4u*)(src + 4);
        uint32_t u[8] = {q0[0], q0[1], q0[2], q0[3], q1[0], q1[1], q1[2], q1[3]};
        U8 uh, um;
#pragma unroll
        for (int d = 0; d < 4; ++d) {
          uh.u[d] = perm_hi(u[2*d+1], u[2*d]);   // hi plane
          um.u[d] = perm_lo(u[2*d+1], u[2*d]);   // mid plane
        }
        short8 ah = uh.v, am = um.v;
#pragma unroll
        for (int ntl = 0; ntl < 2; ++ntl) {
          acc2[ntl] = mfma16(ah, w2m[kt*2+ntl], acc2[ntl]);
          acc2[ntl] = mfma16(am, w2h[kt*2+ntl], acc2[ntl]);
          acc2[ntl] = mfma16(ah, w2h[kt*2+ntl], acc2[ntl]);
        }
      }

      // layer-3 partial over this wave's 32 cols
      v4f part = (v4f){0.f, 0.f, 0.f, 0.f};
#pragma unroll
      for (int ntl = 0; ntl < 2; ++ntl)
#pragma unroll
        for (int r = 0; r < 4; ++r)
          part[r] += fmaxf(acc2[ntl][r], 0.f) * W3c[ntl];
#pragma unroll
      for (int r = 0; r < 4; ++r) part[r] = red16(part[r]);   // VALU butterfly

      // spread store: lane (gq, o<4) writes row mt*16+4gq+o, one ds_write
      const float pv = (o & 2) ? ((o & 1) ? part[3] : part[2])
                               : ((o & 1) ? part[1] : part[0]);
      if (o < 4) sAct[buf][mt*16 + 4*gq + o][wave] = pv;
    }

    __syncthreads();   // B2: partials visible; sH reads done (WAR for t+1)

    // act = sum of 4 member partials + b3
#pragma unroll
    for (int mt = 0; mt < 2; ++mt) {
      v4f pa = *(const v4f*)&sAct[buf][mt*16 + o][0];
      act[mt] = ((pa[0] + pa[1]) + (pa[2] + pa[3])) + b3v;
    }
    if (wave == 0 && gq == 0) {
#pragma unroll
      for (int mt = 0; mt < 2; ++mt)
        sOut[(mt*16 + o) * T + t] = act[mt];
    }

    // roll prefetched inputs
#pragma unroll
    for (int mt = 0; mt < 2; ++mt) {
      sa[mt] = nsa[mt]; fb[mt] = nfb[mt]; exr[mt] = nex[mt];
      m0[mt] = nm0[mt]; m1[mt] = nm1[mt]; m2[mt] = nm2[mt];
    }
    buf ^= 1;
  }

  // ---- coalesced output flush ----
  __syncthreads();
  float* obase = out + (size_t)row0 * T;
  for (int idx = tid; idx < BLK_ROWS * T; idx += NTHREADS)
    obase[idx] = sOut[idx];
}

}  // namespace

extern "C" void kernel_launch(void* const* d_in, const int* in_sizes, int n_in,
                              void* d_out, int out_size, void* d_ws, size_t ws_size,
                              hipStream_t stream) {
  const float* proj  = (const float*)d_in[0];
  const float* idm   = (const float*)d_in[1];
  const float* merg  = (const float*)d_in[2];
  const float* W1    = (const float*)d_in[3];
  const float* b1    = (const float*)d_in[4];
  const float* W2    = (const float*)d_in[5];
  const float* b2    = (const float*)d_in[6];
  const float* W3    = (const float*)d_in[7];
  const float* b3    = (const float*)d_in[8];
  const float* smean = (const float*)d_in[9];
  const float* svar  = (const float*)d_in[10];
  // d_in[11] = rollout_len (fixed 50)

  dim3 grid(NB / BLK_ROWS);   // 1024 blocks -> 4 per CU (VGPR<=128 permitting)
  dim3 block(NTHREADS);       // 256 threads = 4 waves, 32 rows
  hipLaunchKernelGGL(fwdsim8, grid, block, 0, stream,
                     proj, idm, merg, W1, b1, W2, b2, W3, b3, smean, svar,
                     (float*)d_out);
}

// Round 5
// 372.846 us; speedup vs baseline: 1.9329x; 1.0215x over previous
//
#include <hip/hip_runtime.h>
#include <math.h>
#include <stdint.h>

namespace {

constexpr int T = 50;
constexpr int NB = 32768;
constexpr int H = 128;
constexpr int NTHREADS = 256;   // 4 waves; each wave owns 32 output cols
constexpr int BLK_ROWS = 32;    // 2 M-tiles of 16 rows; 1024 blocks = 4/CU
constexpr int SH_STRIDE = 132;  // u32 words per h row (128 + 4 pad)

typedef float v4f __attribute__((ext_vector_type(4)));
typedef float v2f __attribute__((ext_vector_type(2)));
typedef unsigned int v4u __attribute__((ext_vector_type(4)));
typedef short short8 __attribute__((ext_vector_type(8)));

union FU { float f; uint32_t u; };
union U8 { uint32_t u[4]; short8 v; };

// v_perm_b32 byte-select packers (1 VALU op each)
__device__ __forceinline__ uint32_t perm_hi(uint32_t odd, uint32_t even) {
  // top16(odd) : top16(even)
  return __builtin_amdgcn_perm(odd, even, 0x07060302u);
}
__device__ __forceinline__ uint32_t perm_lo(uint32_t odd, uint32_t even) {
  // low16(odd) : low16(even)
  return __builtin_amdgcn_perm(odd, even, 0x05040100u);
}

// 2-way bf16 split, raw words: top16(araw)=hi plane, top16(rraw)=mid plane
__device__ __forceinline__ void split2raw(float a, uint32_t& araw, uint32_t& rraw) {
  FU c0; c0.f = a;
  FU fh; fh.u = c0.u & 0xFFFF0000u;
  FU r;  r.f  = a - fh.f;   // exact
  araw = c0.u; rraw = r.u;
}
// 3-way exact bf16 split (prologue only)
__device__ __forceinline__ void split3(float a, uint32_t& hi, uint32_t& mid, uint32_t& lo) {
  FU c0; c0.f = a;
  uint32_t uh = c0.u & 0xFFFF0000u;
  FU fh; fh.u = uh;
  float r1 = a - fh.f;
  FU c1; c1.f = r1;
  uint32_t um = c1.u & 0xFFFF0000u;
  FU fm; fm.u = um;
  float r2 = r1 - fm.f;
  FU c2; c2.f = r2;
  hi = uh; mid = um; lo = c2.u;
}

__device__ __forceinline__ v4f mfma16(short8 a, short8 b, v4f c) {
  return __builtin_amdgcn_mfma_f32_16x16x32_bf16(a, b, c, 0, 0, 0);
}

// LDS-only block barrier: drains lgkm (DS) but NOT vmcnt, so global
// prefetch loads stay in flight across the barrier (cross-wave data is
// exclusively LDS here; __syncthreads' vmcnt(0) drain stalls every wave
// on HBM latency once per step).
__device__ __forceinline__ void block_sync_lds() {
  asm volatile("s_waitcnt lgkmcnt(0)" ::: "memory");
  __builtin_amdgcn_s_barrier();
  asm volatile("" ::: "memory");
}

// VALU-pipe butterfly add (replaces ds_bpermute __shfl_xor)
template<int CTRL>
__device__ __forceinline__ float dpp_radd(float x) {
  FU a; a.f = x;
  FU b; b.u = (uint32_t)__builtin_amdgcn_update_dpp(0, (int)a.u, CTRL, 0xF, 0xF, true);
  return x + b.f;
}
// sum over the 16 lanes of each lane-group (o = lane&15); result in all 16.
__device__ __forceinline__ float red16(float x) {
  x = dpp_radd<0xB1>(x);    // quad_perm xor1
  x = dpp_radd<0x4E>(x);    // quad_perm xor2
  x = dpp_radd<0x141>(x);   // row_half_mirror (xor4)
  x = dpp_radd<0x140>(x);   // row_mirror (xor8)
  return x;
}

__global__ __launch_bounds__(NTHREADS, 2)   // cap 256 VGPR: NO spills (R3 lesson)
void fwdsim9(const float* __restrict__ proj,   // (B, 64)
             const float* __restrict__ idm,    // (B, T, 12)
             const float* __restrict__ merg,   // (B, T, 3)
             const float* __restrict__ W1,     // (73, 128)
             const float* __restrict__ b1,     // (128)
             const float* __restrict__ W2,     // (128, 128)
             const float* __restrict__ b2,     // (128)
             const float* __restrict__ W3,     // (128, 1)
             const float* __restrict__ b3,     // (1)
             const float* __restrict__ smean,  // (6)
             const float* __restrict__ svar,   // (6)
             float* __restrict__ out)          // (B, T)
{
  // h exchange: [row 32][132] packed bf16 hi|mid (col 0..127 live, 4 pad)
  __shared__ __align__(16) uint32_t sH[BLK_ROWS * SH_STRIDE];   // 16896 B
  // layer-3 partials: [buf][row 32][member 4]
  __shared__ __align__(16) float sAct[2][BLK_ROWS][4];          // 1024 B
  // output staging (coalesced flush at end)
  __shared__ __align__(16) float sOut[BLK_ROWS * T];            // 6400 B
  // total 24320 B -> LDS allows 6 blocks/CU; grid gives 4

  const int tid  = threadIdx.x;
  const int wave = tid >> 6;    // 0..3: owns output cols wave*32 .. wave*32+31
  const int lane = tid & 63;
  const int gq   = lane >> 4;   // 0..3
  const int o    = lane & 15;   // 0..15
  const int row0 = blockIdx.x * BLK_ROWS;

  // ---- scalars: xk = v*istd + off with off = -mean*istd ----
  float istd[6], off[6];
#pragma unroll
  for (int c = 0; c < 6; ++c) {
    istd[c] = 1.0f / sqrtf(svar[c]);
    off[c]  = -smean[c] * istd[c];
  }
  const float b3v = b3[0];
  float b1c[2], b2c[2], W3c[2];
#pragma unroll
  for (int ntl = 0; ntl < 2; ++ntl) {
    const int n = (wave * 2 + ntl) * 16 + o;
    b1c[ntl] = b1[n]; b2c[ntl] = b2[n]; W3c[ntl] = W3[n];
  }

  // ---- W1 env rows 64..72 -> persistent register B-frags (2-plane, K pad 32) ----
  short8 ebh[2], ebm[2];
#pragma unroll
  for (int ntl = 0; ntl < 2; ++ntl) {
    const int n = (wave * 2 + ntl) * 16 + o;
    uint32_t hr[8], mr[8];
#pragma unroll
    for (int j = 0; j < 8; ++j) {
      const int k = gq * 8 + j;
      const float w = (k < 9) ? W1[(64 + k) * H + n] : 0.f;
      split2raw(w, hr[j], mr[j]);
    }
    U8 fh, fm;
#pragma unroll
    for (int d = 0; d < 4; ++d) {
      fh.u[d] = perm_hi(hr[2*d+1], hr[2*d]);
      fm.u[d] = perm_hi(mr[2*d+1], mr[2*d]);
    }
    ebh[ntl] = fh.v; ebm[ntl] = fm.v;
  }

  // ---- W1[0:64] 3-plane frags (prologue-only, registers) ----
  short8 w1h[4], w1m[4], w1l[4];   // [kt*2+ntl]
#pragma unroll
  for (int kt = 0; kt < 2; ++kt)
#pragma unroll
    for (int ntl = 0; ntl < 2; ++ntl) {
      const int k0 = kt * 32 + gq * 8;
      const int n  = (wave * 2 + ntl) * 16 + o;
      uint32_t hi[8], mi[8], lo[8];
#pragma unroll
      for (int j = 0; j < 8; ++j) split3(W1[(k0 + j) * H + n], hi[j], mi[j], lo[j]);
      U8 fh, fm, fl;
#pragma unroll
      for (int d = 0; d < 4; ++d) {
        fh.u[d] = perm_hi(hi[2*d+1], hi[2*d]);
        fm.u[d] = perm_hi(mi[2*d+1], mi[2*d]);
        fl.u[d] = perm_hi(lo[2*d+1], lo[2*d]);
      }
      w1h[kt*2+ntl] = fh.v; w1m[kt*2+ntl] = fm.v; w1l[kt*2+ntl] = fl.v;
    }

  // ---- base1 = b1 + proj @ W1[0:64] via 6-term exact-split MFMA -> registers ----
  // base[mt*2+ntl][r] = base1 for row mt*16+4gq+r, col (wave*2+ntl)*16+o
  v4f base[4];
#pragma unroll
  for (int mt = 0; mt < 2; ++mt) {
    const int row = row0 + mt * 16 + o;
    short8 pah[2], pam[2], pal[2];
#pragma unroll
    for (int kt = 0; kt < 2; ++kt) {
      const float* pp = proj + (size_t)row * 64 + kt * 32 + gq * 8;
      v4f p0 = *(const v4f*)pp;
      v4f p1 = *(const v4f*)(pp + 4);
      uint32_t hi[8], mi[8], lo[8];
#pragma unroll
      for (int e = 0; e < 4; ++e) split3(p0[e], hi[e],   mi[e],   lo[e]);
#pragma unroll
      for (int e = 0; e < 4; ++e) split3(p1[e], hi[4+e], mi[4+e], lo[4+e]);
      U8 uh, um, ul;
#pragma unroll
      for (int d = 0; d < 4; ++d) {
        uh.u[d] = perm_hi(hi[2*d+1], hi[2*d]);
        um.u[d] = perm_hi(mi[2*d+1], mi[2*d]);
        ul.u[d] = perm_hi(lo[2*d+1], lo[2*d]);
      }
      pah[kt] = uh.v; pam[kt] = um.v; pal[kt] = ul.v;
    }
#pragma unroll
    for (int ntl = 0; ntl < 2; ++ntl) {
      v4f acc = (v4f){b1c[ntl], b1c[ntl], b1c[ntl], b1c[ntl]};
#pragma unroll
      for (int kt = 0; kt < 2; ++kt) {
        short8 bh = w1h[kt*2+ntl], bm = w1m[kt*2+ntl], bl = w1l[kt*2+ntl];
        acc = mfma16(pah[kt], bl, acc);
        acc = mfma16(pal[kt], bh, acc);
        acc = mfma16(pam[kt], bm, acc);
        acc = mfma16(pah[kt], bm, acc);
        acc = mfma16(pam[kt], bh, acc);
        acc = mfma16(pah[kt], bh, acc);
      }
      base[mt*2+ntl] = acc;
    }
  }

  // ---- W2 -> persistent register B-frags, this wave's 2 col-tiles only ----
  short8 w2h[8], w2m[8];   // [kt*2+ntl], kt 0..3
#pragma unroll
  for (int kt = 0; kt < 4; ++kt)
#pragma unroll
    for (int ntl = 0; ntl < 2; ++ntl) {
      const int k0 = kt * 32 + gq * 8;
      const int n  = (wave * 2 + ntl) * 16 + o;
      uint32_t hr[8], mr[8];
#pragma unroll
      for (int j = 0; j < 8; ++j) split2raw(W2[(k0 + j) * H + n], hr[j], mr[j]);
      U8 fh, fm;
#pragma unroll
      for (int d = 0; d < 4; ++d) {
        fh.u[d] = perm_hi(hr[2*d+1], hr[2*d]);
        fm.u[d] = perm_hi(mr[2*d+1], mr[2*d]);
      }
      w2h[kt*2+ntl] = fh.v;
      w2m[kt*2+ntl] = fm.v;
    }

  // ---- recurrent state: lane handles rows mt*16+o, replicated over gq/waves ----
  float ego_v[2], ego_x[2], act[2] = {0.f, 0.f};
  const float* idmp[2];
  const float* mrgp[2];
  v4f sa[2]; v2f fb[2]; float exr[2], m0[2], m1[2], m2[2];
#pragma unroll
  for (int mt = 0; mt < 2; ++mt) {
    idmp[mt] = idm  + (size_t)(row0 + mt*16 + o) * (T*12);
    mrgp[mt] = merg + (size_t)(row0 + mt*16 + o) * (T*3);
    sa[mt] = *(const v4f*)idmp[mt];
    fb[mt] = *(const v2f*)(idmp[mt] + 4);
    exr[mt] = idmp[mt][11];
    m0[mt] = mrgp[mt][0]; m1[mt] = mrgp[mt][1]; m2[mt] = mrgp[mt][2];
  }

  int buf = 0;

#pragma unroll 1
  for (int t = 0; t < T; ++t) {
    // ======== phase A: state + env ========
    float xk[2][9];
#pragma unroll
    for (int mt = 0; mt < 2; ++mt) {
      const float s0 = sa[mt][0], fv = sa[mt][1], mv = sa[mt][2], s3 = sa[mt][3];
      const float fgx = fb[mt][0], mgx = fb[mt][1];
      const float ex = exr[mt];
      if (t == 0) { ego_v[mt] = s0; ego_x[mt] = s3; }
      else {
        ego_v[mt] += act[mt] * 0.1f;
        ego_x[mt] += ego_v[mt] * 0.1f + act[mt] * 0.005f;
      }
      xk[mt][0] = ego_v[mt]                                       * istd[0] + off[0];
      xk[mt][1] = fv                                              * istd[1] + off[1];
      xk[mt][2] = (ego_v[mt] - fv)                                * istd[2] + off[2];
      xk[mt][3] = (fgx - ego_x[mt])                               * istd[3] + off[3];
      xk[mt][4] = ((ego_v[mt] - mv) * ex)                         * istd[4] + off[4];
      xk[mt][5] = ((mgx - ego_x[mt]) * ex + (1.0f - ex) * 100.0f) * istd[5] + off[5];
      xk[mt][6] = m0[mt]; xk[mt][7] = m1[mt]; xk[mt][8] = m2[mt];
    }

    // issue next-step input loads NOW (pre-barrier): with lgkm-only barriers
    // they stay in flight across the whole step, drained only at next use
    v4f nsa[2]; v2f nfb[2]; float nex[2], nm0[2], nm1[2], nm2[2];
    {
      const int tn = (t + 1 < T) ? t + 1 : t;
#pragma unroll
      for (int mt = 0; mt < 2; ++mt) {
        const float* ip = idmp[mt] + tn * 12;
        nsa[mt] = *(const v4f*)ip;  nfb[mt] = *(const v2f*)(ip + 4);  nex[mt] = ip[11];
        const float* mp = mrgp[mt] + tn * 3;
        nm0[mt] = mp[0]; nm1[mt] = mp[1]; nm2[mt] = mp[2];
      }
    }

    // ---- layer 1 -> packed h -> sH (own 32 cols) ----
#pragma unroll
    for (int mt = 0; mt < 2; ++mt) {
      // env A-frag: A[m=o][k=8gq+j]; dims 9..31 zero
      uint32_t hr[8], mr[8];
#pragma unroll
      for (int j = 0; j < 8; ++j) {
        float v = (gq == 0) ? xk[mt][j] : ((gq == 1 && j == 0) ? xk[mt][8] : 0.f);
        split2raw(v, hr[j], mr[j]);
      }
      U8 uh, um;
#pragma unroll
      for (int d = 0; d < 4; ++d) {
        uh.u[d] = perm_hi(hr[2*d+1], hr[2*d]);
        um.u[d] = perm_hi(mr[2*d+1], mr[2*d]);
      }
      short8 eh = uh.v, em = um.v;

#pragma unroll
      for (int ntl = 0; ntl < 2; ++ntl) {
        v4f a1 = base[mt*2+ntl];
        a1 = mfma16(eh, ebm[ntl], a1);
        a1 = mfma16(em, ebh[ntl], a1);
        a1 = mfma16(eh, ebh[ntl], a1);
#pragma unroll
        for (int r = 0; r < 4; ++r) {
          const float hv = fmaxf(a1[r], 0.f);
          uint32_t hu, ru; split2raw(hv, hu, ru);
          sH[(mt*16 + 4*gq + r) * SH_STRIDE + (wave*2+ntl)*16 + o] = perm_hi(hu, ru);
        }
      }
    }

    block_sync_lds();   // B1: full h visible (vmcnt NOT drained)

    // ======== phase B: layer 2 (full K from sH) + layer-3 partial ========
#pragma unroll
    for (int mt = 0; mt < 2; ++mt) {
      v4f acc2[2];
#pragma unroll
      for (int ntl = 0; ntl < 2; ++ntl)
        acc2[ntl] = (v4f){b2c[ntl], b2c[ntl], b2c[ntl], b2c[ntl]};

#pragma unroll
      for (int kt = 0; kt < 4; ++kt) {
        const uint32_t* src = &sH[(mt*16 + o) * SH_STRIDE + kt*32 + gq*8];
        v4u q0 = *(const v4u*)src;
        v4u q1 = *(const v4u*)(src + 4);
        U8 uh, um;
        uh.u[0] = perm_hi(q0[1], q0[0]);  um.u[0] = perm_lo(q0[1], q0[0]);
        uh.u[1] = perm_hi(q0[3], q0[2]);  um.u[1] = perm_lo(q0[3], q0[2]);
        uh.u[2] = perm_hi(q1[1], q1[0]);  um.u[2] = perm_lo(q1[1], q1[0]);
        uh.u[3] = perm_hi(q1[3], q1[2]);  um.u[3] = perm_lo(q1[3], q1[2]);
        short8 ah = uh.v, am = um.v;
#pragma unroll
        for (int ntl = 0; ntl < 2; ++ntl) {
          acc2[ntl] = mfma16(ah, w2m[kt*2+ntl], acc2[ntl]);
          acc2[ntl] = mfma16(am, w2h[kt*2+ntl], acc2[ntl]);
          acc2[ntl] = mfma16(ah, w2h[kt*2+ntl], acc2[ntl]);
        }
      }

      // layer-3 partial over this wave's 32 cols
      v4f part = (v4f){0.f, 0.f, 0.f, 0.f};
#pragma unroll
      for (int ntl = 0; ntl < 2; ++ntl)
#pragma unroll
        for (int r = 0; r < 4; ++r)
          part[r] += fmaxf(acc2[ntl][r], 0.f) * W3c[ntl];
#pragma unroll
      for (int r = 0; r < 4; ++r) part[r] = red16(part[r]);   // VALU butterfly

      // spread store: lane (gq, o<4) writes row mt*16+4gq+o, one ds_write
      const float pv = (o & 2) ? ((o & 1) ? part[3] : part[2])
                               : ((o & 1) ? part[1] : part[0]);
      if (o < 4) sAct[buf][mt*16 + 4*gq + o][wave] = pv;
    }

    block_sync_lds();   // B2: partials visible; sH reads done (WAR for t+1)

    // act = sum of 4 member partials + b3
#pragma unroll
    for (int mt = 0; mt < 2; ++mt) {
      v4f pa = *(const v4f*)&sAct[buf][mt*16 + o][0];
      act[mt] = ((pa[0] + pa[1]) + (pa[2] + pa[3])) + b3v;
    }
    if (wave == 0 && gq == 0) {
#pragma unroll
      for (int mt = 0; mt < 2; ++mt)
        sOut[(mt*16 + o) * T + t] = act[mt];
    }

    // roll prefetched inputs
#pragma unroll
    for (int mt = 0; mt < 2; ++mt) {
      sa[mt] = nsa[mt]; fb[mt] = nfb[mt]; exr[mt] = nex[mt];
      m0[mt] = nm0[mt]; m1[mt] = nm1[mt]; m2[mt] = nm2[mt];
    }
    buf ^= 1;
  }

  // ---- coalesced output flush ----
  block_sync_lds();
  float* obase = out + (size_t)row0 * T;
  for (int idx = tid; idx < BLK_ROWS * T; idx += NTHREADS)
    obase[idx] = sOut[idx];
}

}  // namespace

extern "C" void kernel_launch(void* const* d_in, const int* in_sizes, int n_in,
                              void* d_out, int out_size, void* d_ws, size_t ws_size,
                              hipStream_t stream) {
  const float* proj  = (const float*)d_in[0];
  const float* idm   = (const float*)d_in[1];
  const float* merg  = (const float*)d_in[2];
  const float* W1    = (const float*)d_in[3];
  const float* b1    = (const float*)d_in[4];
  const float* W2    = (const float*)d_in[5];
  const float* b2    = (const float*)d_in[6];
  const float* W3    = (const float*)d_in[7];
  const float* b3    = (const float*)d_in[8];
  const float* smean = (const float*)d_in[9];
  const float* svar  = (const float*)d_in[10];
  // d_in[11] = rollout_len (fixed 50)

  dim3 grid(NB / BLK_ROWS);   // 1024 blocks -> 4 per CU
  dim3 block(NTHREADS);       // 256 threads = 4 waves, 32 rows
  hipLaunchKernelGGL(fwdsim9, grid, block, 0, stream,
                     proj, idm, merg, W1, b1, W2, b2, W3, b3, smean, svar,
                     (float*)d_out);
}

// Round 7
// 361.432 us; speedup vs baseline: 1.9940x; 1.0316x over previous
//
#include <hip/hip_runtime.h>
#include <math.h>
#include <stdint.h>

namespace {

constexpr int T = 50;
constexpr int NB = 32768;
constexpr int H = 128;
constexpr int NTHREADS = 256;   // 4 waves; each wave owns 32 output cols
constexpr int BLK_ROWS = 32;    // 2 M-tiles of 16 rows
constexpr int SH_STRIDE = 132;  // u32 words per h row (128 + 4 pad)

typedef float v4f __attribute__((ext_vector_type(4)));
typedef float v2f __attribute__((ext_vector_type(2)));
typedef unsigned int v4u __attribute__((ext_vector_type(4)));
typedef short short8 __attribute__((ext_vector_type(8)));

union FU { float f; uint32_t u; };
union U8 { uint32_t u[4]; short8 v; };
union U8Q { v4u q; short8 v; };

// v_perm_b32 byte-select packers (1 VALU op each)
__device__ __forceinline__ uint32_t perm_hi(uint32_t odd, uint32_t even) {
  // top16(odd) : top16(even)
  return __builtin_amdgcn_perm(odd, even, 0x07060302u);
}

// 2-way bf16 split, raw words: top16(araw)=hi plane, top16(rraw)=mid plane
__device__ __forceinline__ void split2raw(float a, uint32_t& araw, uint32_t& rraw) {
  FU c0; c0.f = a;
  FU fh; fh.u = c0.u & 0xFFFF0000u;
  FU r;  r.f  = a - fh.f;   // exact
  araw = c0.u; rraw = r.u;
}
// 3-way exact bf16 split (prologue only)
__device__ __forceinline__ void split3(float a, uint32_t& hi, uint32_t& mid, uint32_t& lo) {
  FU c0; c0.f = a;
  uint32_t uh = c0.u & 0xFFFF0000u;
  FU fh; fh.u = uh;
  float r1 = a - fh.f;
  FU c1; c1.f = r1;
  uint32_t um = c1.u & 0xFFFF0000u;
  FU fm; fm.u = um;
  float r2 = r1 - fm.f;
  FU c2; c2.f = r2;
  hi = uh; mid = um; lo = c2.u;
}

__device__ __forceinline__ v4f mfma16(short8 a, short8 b, v4f c) {
  return __builtin_amdgcn_mfma_f32_16x16x32_bf16(a, b, c, 0, 0, 0);
}

// LDS-only block barrier: drains lgkm (DS) but NOT vmcnt, so global
// prefetch loads stay in flight across the barrier.
__device__ __forceinline__ void block_sync_lds() {
  asm volatile("s_waitcnt lgkmcnt(0)" ::: "memory");
  __builtin_amdgcn_s_barrier();
  asm volatile("" ::: "memory");
}

// VALU-pipe butterfly add (replaces ds_bpermute __shfl_xor)
template<int CTRL>
__device__ __forceinline__ float dpp_radd(float x) {
  FU a; a.f = x;
  FU b; b.u = (uint32_t)__builtin_amdgcn_update_dpp(0, (int)a.u, CTRL, 0xF, 0xF, true);
  return x + b.f;
}
// sum over the 16 lanes of each lane-group (o = lane&15); result in all 16.
__device__ __forceinline__ float red16(float x) {
  x = dpp_radd<0xB1>(x);    // quad_perm xor1
  x = dpp_radd<0x4E>(x);    // quad_perm xor2
  x = dpp_radd<0x141>(x);   // row_half_mirror (xor4)
  x = dpp_radd<0x140>(x);   // row_mirror (xor8)
  return x;
}

__global__ __launch_bounds__(NTHREADS, 2)   // cap 256 total regs: no spills
void fwdsim10(const float* __restrict__ proj,   // (B, 64)
              const float* __restrict__ idm,    // (B, T, 12)
              const float* __restrict__ merg,   // (B, T, 3)
              const float* __restrict__ W1,     // (73, 128)
              const float* __restrict__ b1,     // (128)
              const float* __restrict__ W2,     // (128, 128)
              const float* __restrict__ b2,     // (128)
              const float* __restrict__ W3,     // (128, 1)
              const float* __restrict__ b3,     // (1)
              const float* __restrict__ smean,  // (6)
              const float* __restrict__ svar,   // (6)
              float* __restrict__ out)          // (B, T)
{
  // h exchange: [row 32][132] packed bf16 hi|mid (col 0..127 live, 4 pad)
  __shared__ __align__(16) uint32_t sH[BLK_ROWS * SH_STRIDE];   // 16896 B
  // layer-3 partials: [buf][row 32][member 4]
  __shared__ __align__(16) float sAct[2][BLK_ROWS][4];          // 1024 B
  // output staging (coalesced flush at end)
  __shared__ __align__(16) float sOut[BLK_ROWS * T];            // 6400 B
  // total 24320 B

  const int tid  = threadIdx.x;
  const int wave = tid >> 6;    // 0..3: owns output cols wave*32 .. wave*32+31
  const int lane = tid & 63;
  const int gq   = lane >> 4;   // 0..3
  const int o    = lane & 15;   // 0..15
  const int row0 = blockIdx.x * BLK_ROWS;

  // ---- scalars: xk = v*istd + off with off = -mean*istd ----
  float istd[6], off[6];
#pragma unroll
  for (int c = 0; c < 6; ++c) {
    istd[c] = 1.0f / sqrtf(svar[c]);
    off[c]  = -smean[c] * istd[c];
  }
  const float b3v = b3[0];
  float b1c[2], b2c[2], W3c[2];
#pragma unroll
  for (int ntl = 0; ntl < 2; ++ntl) {
    const int n = (wave * 2 + ntl) * 16 + o;
    b1c[ntl] = b1[n]; b2c[ntl] = b2[n]; W3c[ntl] = W3[n];
  }

  // ---- W1 env rows 64..72 -> persistent register B-frags (2-plane, K pad 32) ----
  short8 ebh[2], ebm[2];
#pragma unroll
  for (int ntl = 0; ntl < 2; ++ntl) {
    const int n = (wave * 2 + ntl) * 16 + o;
    uint32_t hr[8], mr[8];
#pragma unroll
    for (int j = 0; j < 8; ++j) {
      const int k = gq * 8 + j;
      const float w = (k < 9) ? W1[(64 + k) * H + n] : 0.f;
      split2raw(w, hr[j], mr[j]);
    }
    U8 fh, fm;
#pragma unroll
    for (int d = 0; d < 4; ++d) {
      fh.u[d] = perm_hi(hr[2*d+1], hr[2*d]);
      fm.u[d] = perm_hi(mr[2*d+1], mr[2*d]);
    }
    ebh[ntl] = fh.v; ebm[ntl] = fm.v;
  }

  // ---- W1[0:64] 3-plane frags (prologue-only, registers) ----
  short8 w1h[4], w1m[4], w1l[4];   // [kt*2+ntl]
#pragma unroll
  for (int kt = 0; kt < 2; ++kt)
#pragma unroll
    for (int ntl = 0; ntl < 2; ++ntl) {
      const int k0 = kt * 32 + gq * 8;
      const int n  = (wave * 2 + ntl) * 16 + o;
      uint32_t hi[8], mi[8], lo[8];
#pragma unroll
      for (int j = 0; j < 8; ++j) split3(W1[(k0 + j) * H + n], hi[j], mi[j], lo[j]);
      U8 fh, fm, fl;
#pragma unroll
      for (int d = 0; d < 4; ++d) {
        fh.u[d] = perm_hi(hi[2*d+1], hi[2*d]);
        fm.u[d] = perm_hi(mi[2*d+1], mi[2*d]);
        fl.u[d] = perm_hi(lo[2*d+1], lo[2*d]);
      }
      w1h[kt*2+ntl] = fh.v; w1m[kt*2+ntl] = fm.v; w1l[kt*2+ntl] = fl.v;
    }

  // ---- base1 = b1 + proj @ W1[0:64] via 6-term exact-split MFMA -> registers ----
  v4f base[4];
#pragma unroll
  for (int mt = 0; mt < 2; ++mt) {
    const int row = row0 + mt * 16 + o;
    short8 pah[2], pam[2], pal[2];
#pragma unroll
    for (int kt = 0; kt < 2; ++kt) {
      const float* pp = proj + (size_t)row * 64 + kt * 32 + gq * 8;
      v4f p0 = *(const v4f*)pp;
      v4f p1 = *(const v4f*)(pp + 4);
      uint32_t hi[8], mi[8], lo[8];
#pragma unroll
      for (int e = 0; e < 4; ++e) split3(p0[e], hi[e],   mi[e],   lo[e]);
#pragma unroll
      for (int e = 0; e < 4; ++e) split3(p1[e], hi[4+e], mi[4+e], lo[4+e]);
      U8 uh, um, ul;
#pragma unroll
      for (int d = 0; d < 4; ++d) {
        uh.u[d] = perm_hi(hi[2*d+1], hi[2*d]);
        um.u[d] = perm_hi(mi[2*d+1], mi[2*d]);
        ul.u[d] = perm_hi(lo[2*d+1], lo[2*d]);
      }
      pah[kt] = uh.v; pam[kt] = um.v; pal[kt] = ul.v;
    }
#pragma unroll
    for (int ntl = 0; ntl < 2; ++ntl) {
      v4f acc = (v4f){b1c[ntl], b1c[ntl], b1c[ntl], b1c[ntl]};
#pragma unroll
      for (int kt = 0; kt < 2; ++kt) {
        short8 bh = w1h[kt*2+ntl], bm = w1m[kt*2+ntl], bl = w1l[kt*2+ntl];
        acc = mfma16(pah[kt], bl, acc);
        acc = mfma16(pal[kt], bh, acc);
        acc = mfma16(pam[kt], bm, acc);
        acc = mfma16(pah[kt], bm, acc);
        acc = mfma16(pam[kt], bh, acc);
        acc = mfma16(pah[kt], bh, acc);
      }
      base[mt*2+ntl] = acc;
    }
  }

  // ---- W2 -> persistent register B-frags (virtual-K form) ----
  // w2v0/w2v1: hi-plane values DUPLICATED into both 16-bit slots of each u32,
  // so the raw sH words (elem pair = (mid,hi)) multiply as (hi+mid)*W2hi with
  // ZERO unpack perms. w2m: mid plane, paired with the hi-extracted A-frag.
  short8 w2v0[8], w2v1[8], w2m[8];   // [kt*2+ntl]  (96 VGPR total)
#pragma unroll
  for (int kt = 0; kt < 4; ++kt)
#pragma unroll
    for (int ntl = 0; ntl < 2; ++ntl) {
      const int k0 = kt * 32 + gq * 8;
      const int n  = (wave * 2 + ntl) * 16 + o;
      uint32_t hr[8], mr[8];
#pragma unroll
      for (int j = 0; j < 8; ++j) split2raw(W2[(k0 + j) * H + n], hr[j], mr[j]);
      U8 fv0, fv1, fm;
#pragma unroll
      for (int d = 0; d < 4; ++d) {
        const uint32_t h0 = hr[d]   & 0xFFFF0000u;   // col k0+d
        const uint32_t h1 = hr[4+d] & 0xFFFF0000u;   // col k0+4+d
        fv0.u[d] = h0 | (h0 >> 16);                  // dup bf16 into both slots
        fv1.u[d] = h1 | (h1 >> 16);
        fm.u[d]  = perm_hi(mr[2*d+1], mr[2*d]);      // mid plane, col pairs
      }
      w2v0[kt*2+ntl] = fv0.v;
      w2v1[kt*2+ntl] = fv1.v;
      w2m[kt*2+ntl]  = fm.v;
    }

  // ---- recurrent state: lane handles rows mt*16+o, replicated over gq/waves ----
  float ego_v[2], ego_x[2], act[2] = {0.f, 0.f};
  const float* idmp[2];
  const float* mrgp[2];
  v4f sa[2]; v2f fb[2]; float exr[2], m0[2], m1[2], m2[2];
#pragma unroll
  for (int mt = 0; mt < 2; ++mt) {
    idmp[mt] = idm  + (size_t)(row0 + mt*16 + o) * (T*12);
    mrgp[mt] = merg + (size_t)(row0 + mt*16 + o) * (T*3);
    sa[mt] = *(const v4f*)idmp[mt];
    fb[mt] = *(const v2f*)(idmp[mt] + 4);
    exr[mt] = idmp[mt][11];
    m0[mt] = mrgp[mt][0]; m1[mt] = mrgp[mt][1]; m2[mt] = mrgp[mt][2];
  }

  int buf = 0;

#pragma unroll 1
  for (int t = 0; t < T; ++t) {
    // ======== phase A: state + env ========
    float xk[2][9];
#pragma unroll
    for (int mt = 0; mt < 2; ++mt) {
      const float s0 = sa[mt][0], fv = sa[mt][1], mv = sa[mt][2], s3 = sa[mt][3];
      const float fgx = fb[mt][0], mgx = fb[mt][1];
      const float ex = exr[mt];
      if (t == 0) { ego_v[mt] = s0; ego_x[mt] = s3; }
      else {
        ego_v[mt] += act[mt] * 0.1f;
        ego_x[mt] += ego_v[mt] * 0.1f + act[mt] * 0.005f;
      }
      xk[mt][0] = ego_v[mt]                                       * istd[0] + off[0];
      xk[mt][1] = fv                                              * istd[1] + off[1];
      xk[mt][2] = (ego_v[mt] - fv)                                * istd[2] + off[2];
      xk[mt][3] = (fgx - ego_x[mt])                               * istd[3] + off[3];
      xk[mt][4] = ((ego_v[mt] - mv) * ex)                         * istd[4] + off[4];
      xk[mt][5] = ((mgx - ego_x[mt]) * ex + (1.0f - ex) * 100.0f) * istd[5] + off[5];
      xk[mt][6] = m0[mt]; xk[mt][7] = m1[mt]; xk[mt][8] = m2[mt];
    }

    // reload next step's inputs IN PLACE (sa/fb/... just consumed above).
    // With lgkm-only barriers these loads fly across the whole step; no
    // roll moves, no shadow registers.
    {
      const int tn = (t + 1 < T) ? t + 1 : t;
#pragma unroll
      for (int mt = 0; mt < 2; ++mt) {
        const float* ip = idmp[mt] + tn * 12;
        sa[mt] = *(const v4f*)ip;  fb[mt] = *(const v2f*)(ip + 4);  exr[mt] = ip[11];
        const float* mp = mrgp[mt] + tn * 3;
        m0[mt] = mp[0]; m1[mt] = mp[1]; m2[mt] = mp[2];
      }
    }

    // ---- layer 1 -> packed h -> sH (own 32 cols) ----
#pragma unroll
    for (int mt = 0; mt < 2; ++mt) {
      // env A-frag: A[m=o][k=8gq+j]; dims 9..31 zero
      uint32_t hr[8], mr[8];
#pragma unroll
      for (int j = 0; j < 8; ++j) {
        float v = (gq == 0) ? xk[mt][j] : ((gq == 1 && j == 0) ? xk[mt][8] : 0.f);
        split2raw(v, hr[j], mr[j]);
      }
      U8 uh, um;
#pragma unroll
      for (int d = 0; d < 4; ++d) {
        uh.u[d] = perm_hi(hr[2*d+1], hr[2*d]);
        um.u[d] = perm_hi(mr[2*d+1], mr[2*d]);
      }
      short8 eh = uh.v, em = um.v;

#pragma unroll
      for (int ntl = 0; ntl < 2; ++ntl) {
        v4f a1 = base[mt*2+ntl];
        a1 = mfma16(eh, ebm[ntl], a1);
        a1 = mfma16(em, ebh[ntl], a1);
        a1 = mfma16(eh, ebh[ntl], a1);
#pragma unroll
        for (int r = 0; r < 4; ++r) {
          const float hv = fmaxf(a1[r], 0.f);
          uint32_t hu, ru; split2raw(hv, hu, ru);
          sH[(mt*16 + 4*gq + r) * SH_STRIDE + (wave*2+ntl)*16 + o] = perm_hi(hu, ru);
        }
      }
    }

    block_sync_lds();   // B1: full h visible (vmcnt NOT drained)

    // ======== phase B: layer 2 (full K from sH) + layer-3 partial ========
#pragma unroll
    for (int mt = 0; mt < 2; ++mt) {
      v4f acc2[2];
#pragma unroll
      for (int ntl = 0; ntl < 2; ++ntl)
        acc2[ntl] = (v4f){b2c[ntl], b2c[ntl], b2c[ntl], b2c[ntl]};

#pragma unroll
      for (int kt = 0; kt < 4; ++kt) {
        const uint32_t* src = &sH[(mt*16 + o) * SH_STRIDE + kt*32 + gq*8];
        U8Q c0, c1;
        c0.q = *(const v4u*)src;         // raw words: elem pair = (mid,hi)
        c1.q = *(const v4u*)(src + 4);
        U8 uh;                            // hi-plane extraction (4 perms only)
        uh.u[0] = perm_hi(c0.q[1], c0.q[0]);
        uh.u[1] = perm_hi(c0.q[3], c0.q[2]);
        uh.u[2] = perm_hi(c1.q[1], c1.q[0]);
        uh.u[3] = perm_hi(c1.q[3], c1.q[2]);
        short8 aq0 = c0.v, aq1 = c1.v, ah = uh.v;
#pragma unroll
        for (int ntl = 0; ntl < 2; ++ntl) {
          acc2[ntl] = mfma16(aq0, w2v0[kt*2+ntl], acc2[ntl]);  // (hi+mid)*W2hi (half1)
          acc2[ntl] = mfma16(aq1, w2v1[kt*2+ntl], acc2[ntl]);  // (hi+mid)*W2hi (half2)
          acc2[ntl] = mfma16(ah,  w2m[kt*2+ntl],  acc2[ntl]);  // hi*W2mid
        }
      }

      // layer-3 partial over this wave's 32 cols
      v4f part = (v4f){0.f, 0.f, 0.f, 0.f};
#pragma unroll
      for (int ntl = 0; ntl < 2; ++ntl)
#pragma unroll
        for (int r = 0; r < 4; ++r)
          part[r] += fmaxf(acc2[ntl][r], 0.f) * W3c[ntl];
#pragma unroll
      for (int r = 0; r < 4; ++r) part[r] = red16(part[r]);   // VALU butterfly

      // spread store: lane (gq, o<4) writes row mt*16+4gq+o, one ds_write
      const float pv = (o & 2) ? ((o & 1) ? part[3] : part[2])
                               : ((o & 1) ? part[1] : part[0]);
      if (o < 4) sAct[buf][mt*16 + 4*gq + o][wave] = pv;
    }

    block_sync_lds();   // B2: partials visible; sH reads done (WAR for t+1)

    // act = sum of 4 member partials + b3
#pragma unroll
    for (int mt = 0; mt < 2; ++mt) {
      v4f pa = *(const v4f*)&sAct[buf][mt*16 + o][0];
      act[mt] = ((pa[0] + pa[1]) + (pa[2] + pa[3])) + b3v;
    }
    if (wave == 0 && gq == 0) {
#pragma unroll
      for (int mt = 0; mt < 2; ++mt)
        sOut[(mt*16 + o) * T + t] = act[mt];
    }
    buf ^= 1;
  }

  // ---- coalesced output flush ----
  block_sync_lds();
  float* obase = out + (size_t)row0 * T;
  for (int idx = tid; idx < BLK_ROWS * T; idx += NTHREADS)
    obase[idx] = sOut[idx];
}

}  // namespace

extern "C" void kernel_launch(void* const* d_in, const int* in_sizes, int n_in,
                              void* d_out, int out_size, void* d_ws, size_t ws_size,
                              hipStream_t stream) {
  const float* proj  = (const float*)d_in[0];
  const float* idm   = (const float*)d_in[1];
  const float* merg  = (const float*)d_in[2];
  const float* W1    = (const float*)d_in[3];
  const float* b1    = (const float*)d_in[4];
  const float* W2    = (const float*)d_in[5];
  const float* b2    = (const float*)d_in[6];
  const float* W3    = (const float*)d_in[7];
  const float* b3    = (const float*)d_in[8];
  const float* smean = (const float*)d_in[9];
  const float* svar  = (const float*)d_in[10];
  // d_in[11] = rollout_len (fixed 50)

  dim3 grid(NB / BLK_ROWS);   // 1024 blocks
  dim3 block(NTHREADS);       // 256 threads = 4 waves, 32 rows
  hipLaunchKernelGGL(fwdsim10, grid, block, 0, stream,
                     proj, idm, merg, W1, b1, W2, b2, W3, b3, smean, svar,
                     (float*)d_out);
}